// Round 1
// baseline (32.955 us; speedup 1.0000x reference)
//
#include <hip/hip_runtime.h>

#define NBINS 64
#define FINE 512                     // 8 sub-bins per coarse bin
#define PIX_PER_CH (512 * 512)       // 262144
#define CH_TOTAL 24                  // 2 inputs x (4*3) channels
#define BLOCKS_PER_CH 32
#define PIX_PER_BLOCK (PIX_PER_CH / BLOCKS_PER_CH)   // 8192
#define THREADS 512                  // 8 waves
#define HBLOCKS (CH_TOTAL * BLOCKS_PER_CH)           // 768 = 3 per CU

#define O_LO (-36)                   // taps: d=(o+0.5)/8-0.5 in [-5,5); o in [-36,43]
#define NTAP 80
#define TAPS_PER_WAVE (NTAP / 8)     // 10

#define PAD(i) ((i) + ((i) >> 4))    // +1 pad per 16 words
#define PFINE (FINE + (FINE >> 4))   // 544

#define GPART_ROW (CH_TOTAL * NBINS) // 1536 floats per blk row
#define GPART_FLOATS (BLOCKS_PER_CH * GPART_ROW)     // 49152

__device__ __forceinline__ float wexp(float d) {
    return __expf(-0.5f * d * d);
}

// ws layout: [0, 196608) g_part f32 [blk][ch][bin] | [196608, 196612) u32 counter
//   counter is zeroed by a 4-byte hipMemsetAsync node before the kernel.

__global__ __launch_bounds__(THREADS) void fused_kernel(
        const float* __restrict__ pred, const float* __restrict__ target,
        float* __restrict__ g_part, unsigned int* __restrict__ g_cnt,
        float* __restrict__ out) {
    __shared__ int fineI[PFINE];     // padded per-block fine histogram
    __shared__ float hpart[NBINS];   // cross-wave partial coarse bins
    __shared__ int sLo, sHi;
    __shared__ int isLast;
    // finalize-phase LDS (last block only; budget still ~9 KB total)
    __shared__ float h[CH_TOTAL * NBINS];   // 1536
    __shared__ float csum[96];
    __shared__ float inv[CH_TOTAL];
    __shared__ float wred[8];

    const int tid = threadIdx.x;
    const int lane = tid & 63, wave = tid >> 6;
    const int b = blockIdx.x;
    const int gch = b / BLOCKS_PER_CH;        // 0..23
    const int blk = b - gch * BLOCKS_PER_CH;  // 0..31
    const float4* src4 = reinterpret_cast<const float4*>(
        (gch < 12 ? pred + gch * PIX_PER_CH
                  : target + (gch - 12) * PIX_PER_CH)
        + blk * PIX_PER_BLOCK);

    for (int i = tid; i < PFINE; i += THREADS) fineI[i] = 0;
    if (tid < NBINS) hpart[tid] = 0.f;
    if (tid == 0) { sLo = 0; sHi = 0; }
    __syncthreads();

    // one memory epoch: all 4 float4 loads issued back-to-back, independent
    float4 v[4];
    #pragma unroll
    for (int it = 0; it < 4; ++it)
        v[it] = src4[it * THREADS + tid];

    const float HI = 1.0f - 1e-6f;
    int cLo = 0, cHi = 0;

    #pragma unroll
    for (int it = 0; it < 4; ++it) {
        float xs[4] = {v[it].x, v[it].y, v[it].z, v[it].w};
        #pragma unroll
        for (int k = 0; k < 4; ++k) {
            float y = fmaf(xs[k], 0.5f, 0.5f);
            if (y <= 0.f) {
                ++cLo;               // clipped: analytic fold, no scatter
            } else if (y >= HI) {
                ++cHi;
            } else {
                int f = (int)(y * (float)FINE);      // [0, 511]
                atomicAdd(&fineI[PAD(f)], 1);
            }
        }
    }

    // wave-reduce clip counts, one LDS atomic per wave
    #pragma unroll
    for (int off = 32; off; off >>= 1) {
        cLo += __shfl_down(cLo, off, 64);
        cHi += __shfl_down(cHi, off, 64);
    }
    if (lane == 0) {
        if (cLo) atomicAdd(&sLo, cLo);
        if (cHi) atomicAdd(&sHi, cHi);
    }
    __syncthreads();

    // Fused conv, bin-per-lane: lane owns coarse bin `lane`; wave w covers
    // taps [w*10, w*10+10). Read stride ~8.5 words -> ~2 lanes/bank (free).
    float acc = 0.f;
    #pragma unroll
    for (int s = 0; s < TAPS_PER_WAVE; ++s) {
        int o = O_LO + wave * TAPS_PER_WAVE + s;
        float d = fmaf((float)o + 0.5f, 0.125f, -0.5f);
        float kv = wexp(d);
        int idx = (lane << 3) + o;
        if (idx >= 0 && idx < FINE)
            acc = fmaf((float)fineI[PAD(idx)], kv, acc);
    }
    // fold clipped-pixel mass into edge bins analytically, per block (linear,
    // so identical to deferred folding). Only wave 0 (one lane per bin).
    if (wave == 0) {
        if (lane <= 6)
            acc = fmaf((float)sLo, wexp(-0.5f - (float)lane), acc);
        if (lane >= 57) {
            float t = fmaf(HI, 64.f, -0.5f);
            acc = fmaf((float)sHi, wexp(t - (float)lane), acc);
        }
    }
    if (acc != 0.f) atomicAdd(&hpart[lane], acc);   // 8-way cross-wave combine
    __syncthreads();

    // coalesced 256 B row store: [blk][ch][bin]; every slot written -> no init
    if (tid < NBINS)
        g_part[blk * GPART_ROW + gch * NBINS + tid] = hpart[tid];
    __syncthreads();   // barrier drains vmcnt: all waves' stores at L2

    // last-block-done: release (wb L2) -> counter; only the true last block
    // proceeds -- no spinning, no second kernel dispatch.
    if (tid == 0) {
        __threadfence();
        isLast = (atomicAdd(g_cnt, 1u) == HBLOCKS - 1) ? 1 : 0;
    }
    __syncthreads();
    if (!isLast) return;
    __threadfence();   // acquire: invalidate L1/L2 before reading other XCDs' rows

    // ---- finalize, 512 threads of the last block ----
    // sum the 32 per-block rows; fully coalesced (64 lanes x 16 B contiguous)
    if (tid < 384) {
        const float4* gp = reinterpret_cast<const float4*>(g_part) + tid;
        float4 s = make_float4(0.f, 0.f, 0.f, 0.f);
        #pragma unroll 8
        for (int r = 0; r < BLOCKS_PER_CH; ++r) {
            float4 w = gp[r * (GPART_ROW / 4)];
            s.x += w.x; s.y += w.y; s.z += w.z; s.w += w.w;
        }
        reinterpret_cast<float4*>(h)[tid] = s;
    }
    __syncthreads();

    // per-channel sums: 4 partial lanes per channel, then combine
    if (tid < 96) {
        int c = tid >> 2, q = tid & 3;
        float s = 0.f;
        #pragma unroll
        for (int j = 0; j < 16; ++j) s += h[c * NBINS + q * 16 + j];
        csum[tid] = s;
    }
    __syncthreads();
    if (tid < CH_TOTAL)
        inv[tid] = 1.0f / (csum[4 * tid] + csum[4 * tid + 1]
                         + csum[4 * tid + 2] + csum[4 * tid + 3] + 1e-8f);
    __syncthreads();

    float a2 = 0.f;
    for (int i = tid; i < 12 * NBINS; i += THREADS) {   // 768
        int c = i >> 6;
        float pa = h[i] * inv[c];
        float pb = h[12 * NBINS + i] * inv[12 + c];
        a2 += fabsf(pa - pb);
    }
    #pragma unroll
    for (int off = 32; off; off >>= 1) a2 += __shfl_down(a2, off, 64);
    if ((tid & 63) == 0) wred[tid >> 6] = a2;
    __syncthreads();
    if (tid == 0) {
        float total = 0.f;
        #pragma unroll
        for (int w2 = 0; w2 < 8; ++w2) total += wred[w2];
        out[0] = total * (1.0f / 768.0f);
    }
}

extern "C" void kernel_launch(void* const* d_in, const int* in_sizes, int n_in,
                              void* d_out, int out_size, void* d_ws, size_t ws_size,
                              hipStream_t stream) {
    const float* pred = (const float*)d_in[0];
    const float* target = (const float*)d_in[1];
    float* out = (float*)d_out;
    float* g_part = (float*)d_ws;                                    // 49152 f32
    unsigned int* g_cnt =
        (unsigned int*)((char*)d_ws + GPART_FLOATS * sizeof(float)); // 1 u32

    hipMemsetAsync(g_cnt, 0, sizeof(unsigned int), stream);          // 4 B node
    fused_kernel<<<HBLOCKS, THREADS, 0, stream>>>(pred, target, g_part, g_cnt, out);
}

// Round 3
// 30.278 us; speedup vs baseline: 1.0884x; 1.0884x over previous
//
#include <hip/hip_runtime.h>

#define NBINS 64
#define FINE 512                     // 8 sub-bins per coarse bin
#define PIX_PER_CH (512 * 512)       // 262144
#define CH_TOTAL 24                  // 2 inputs x (4*3) channels
#define BLOCKS_PER_CH 32
#define PIX_PER_BLOCK (PIX_PER_CH / BLOCKS_PER_CH)   // 8192
#define THREADS 512                  // 8 waves
#define HBLOCKS (CH_TOTAL * BLOCKS_PER_CH)           // 768 = 3 per CU

#define O_LO (-36)                   // taps: d=(o+0.5)/8-0.5 in [-5,5); o in [-36,43]
#define NTAP 80
#define TAPS_PER_WAVE (NTAP / 8)     // 10

#define PAD(i) ((i) + ((i) >> 4))    // +1 pad per 16 words
#define PFINE (FINE + (FINE >> 4))   // 544

__device__ __forceinline__ float wexp(float d) {
    return __expf(-0.5f * d * d);
}

// ws layout (all zeroed by ONE 6.4 KB memset node each launch):
//   [0, 6144)     g_hist  f32[24][64]   atomic-accumulated coarse histograms
//   [6144, 6240)  chctr   u32[24]       per-channel arrival counters
//   [6240, 6244)  gctr    u32           global arrival counter
//
// Sync protocol (proven correct in round 0, absmax 0.0): release =
// __threadfence() before arrival atomic; acquire = __threadfence() after
// observing the last arrival. Hierarchical counters cap same-address
// contention at 32 (vs 768 on a single counter).

__global__ __launch_bounds__(THREADS) void fused_kernel(
        const float* __restrict__ pred, const float* __restrict__ target,
        float* __restrict__ g_hist, unsigned int* __restrict__ chctr,
        unsigned int* __restrict__ gctr, float* __restrict__ out) {
    __shared__ int fineI[PFINE];     // padded per-block fine histogram
    __shared__ float hpart[NBINS];   // cross-wave partial coarse bins
    __shared__ int sLo, sHi;
    __shared__ int lastFlag;
    // finalize-phase LDS (last block only)
    __shared__ float h[CH_TOTAL * NBINS];   // 1536
    __shared__ float csum[96];
    __shared__ float inv[CH_TOTAL];
    __shared__ float wred[8];

    const int tid = threadIdx.x;
    const int lane = tid & 63, wave = tid >> 6;
    const int b = blockIdx.x;
    const int gch = b / BLOCKS_PER_CH;        // 0..23
    const int blk = b - gch * BLOCKS_PER_CH;  // 0..31
    const float4* src4 = reinterpret_cast<const float4*>(
        (gch < 12 ? pred + gch * PIX_PER_CH
                  : target + (gch - 12) * PIX_PER_CH)
        + blk * PIX_PER_BLOCK);

    for (int i = tid; i < PFINE; i += THREADS) fineI[i] = 0;
    if (tid < NBINS) hpart[tid] = 0.f;
    if (tid == 0) { sLo = 0; sHi = 0; }
    __syncthreads();

    // one memory epoch: all 4 float4 loads issued back-to-back, independent
    float4 v[4];
    #pragma unroll
    for (int it = 0; it < 4; ++it)
        v[it] = src4[it * THREADS + tid];

    const float HI = 1.0f - 1e-6f;
    int cLo = 0, cHi = 0;

    #pragma unroll
    for (int it = 0; it < 4; ++it) {
        float xs[4] = {v[it].x, v[it].y, v[it].z, v[it].w};
        #pragma unroll
        for (int k = 0; k < 4; ++k) {
            float y = fmaf(xs[k], 0.5f, 0.5f);
            if (y <= 0.f) {
                ++cLo;               // clipped: analytic fold, no scatter
            } else if (y >= HI) {
                ++cHi;
            } else {
                int f = (int)(y * (float)FINE);      // [0, 511]
                atomicAdd(&fineI[PAD(f)], 1);
            }
        }
    }

    // wave-reduce clip counts, one LDS atomic per wave
    #pragma unroll
    for (int off = 32; off; off >>= 1) {
        cLo += __shfl_down(cLo, off, 64);
        cHi += __shfl_down(cHi, off, 64);
    }
    if (lane == 0) {
        if (cLo) atomicAdd(&sLo, cLo);
        if (cHi) atomicAdd(&sHi, cHi);
    }
    __syncthreads();

    // Fused conv, bin-per-lane: lane owns coarse bin `lane`; wave w covers
    // taps [w*10, w*10+10). Read stride ~8.5 words -> ~2 lanes/bank (free).
    float acc = 0.f;
    #pragma unroll
    for (int s = 0; s < TAPS_PER_WAVE; ++s) {
        int o = O_LO + wave * TAPS_PER_WAVE + s;
        float d = fmaf((float)o + 0.5f, 0.125f, -0.5f);
        float kv = wexp(d);
        int idx = (lane << 3) + o;
        if (idx >= 0 && idx < FINE)
            acc = fmaf((float)fineI[PAD(idx)], kv, acc);
    }
    // fold clipped-pixel mass into edge bins analytically, per block (linear,
    // so identical to deferred folding). Only wave 0 (one lane per bin).
    if (wave == 0) {
        if (lane <= 6)
            acc = fmaf((float)sLo, wexp(-0.5f - (float)lane), acc);
        if (lane >= 57) {
            float t = fmaf(HI, 64.f, -0.5f);
            acc = fmaf((float)sHi, wexp(t - (float)lane), acc);
        }
    }
    if (acc != 0.f) atomicAdd(&hpart[lane], acc);   // 8-way cross-wave combine
    __syncthreads();

    // accumulate coarse bins straight into the global per-channel histogram:
    // 64 float atomics per block (wave 0), 32-way contention per address.
    if (tid < NBINS)
        atomicAdd(&g_hist[gch * NBINS + tid], hpart[tid]);

    // hierarchical last-block-done arrival. tid 0 is in wave 0, so its
    // vmcnt-draining fence covers the whole wave's g_hist atomics.
    if (tid == 0) {
        __threadfence();             // release
        int last = 0;
        if (atomicAdd(&chctr[gch], 1u) == BLOCKS_PER_CH - 1) {
            if (atomicAdd(gctr, 1u) == CH_TOTAL - 1) last = 1;
        }
        lastFlag = last;
    }
    __syncthreads();
    if (!lastFlag) return;
    __threadfence();                 // acquire

    // ---- finalize, 512 threads of the last block; reads only 6 KB ----
    for (int i = tid; i < CH_TOTAL * NBINS; i += THREADS)
        h[i] = __hip_atomic_load(&g_hist[i], __ATOMIC_RELAXED,
                                 __HIP_MEMORY_SCOPE_AGENT);
    __syncthreads();

    // per-channel sums: 4 partial lanes per channel, then combine
    if (tid < 96) {
        int c = tid >> 2, q = tid & 3;
        float s = 0.f;
        #pragma unroll
        for (int j = 0; j < 16; ++j) s += h[c * NBINS + q * 16 + j];
        csum[tid] = s;
    }
    __syncthreads();
    if (tid < CH_TOTAL)
        inv[tid] = 1.0f / (csum[4 * tid] + csum[4 * tid + 1]
                         + csum[4 * tid + 2] + csum[4 * tid + 3] + 1e-8f);
    __syncthreads();

    float a2 = 0.f;
    for (int i = tid; i < 12 * NBINS; i += THREADS) {   // 768
        int c = i >> 6;
        float pa = h[i] * inv[c];
        float pb = h[12 * NBINS + i] * inv[12 + c];
        a2 += fabsf(pa - pb);
    }
    #pragma unroll
    for (int off = 32; off; off >>= 1) a2 += __shfl_down(a2, off, 64);
    if ((tid & 63) == 0) wred[tid >> 6] = a2;
    __syncthreads();
    if (tid == 0) {
        float total = 0.f;
        #pragma unroll
        for (int w2 = 0; w2 < 8; ++w2) total += wred[w2];
        out[0] = total * (1.0f / 768.0f);
    }
}

extern "C" void kernel_launch(void* const* d_in, const int* in_sizes, int n_in,
                              void* d_out, int out_size, void* d_ws, size_t ws_size,
                              hipStream_t stream) {
    const float* pred = (const float*)d_in[0];
    const float* target = (const float*)d_in[1];
    float* out = (float*)d_out;
    float* g_hist = (float*)d_ws;                                    // 1536 f32
    unsigned int* chctr = (unsigned int*)((char*)d_ws + 6144);       // 24 u32
    unsigned int* gctr  = (unsigned int*)((char*)d_ws + 6240);       // 1 u32

    hipMemsetAsync(d_ws, 0, 6400, stream);   // one tiny fill node: hist+counters
    fused_kernel<<<HBLOCKS, THREADS, 0, stream>>>(pred, target,
                                                  g_hist, chctr, gctr, out);
}

// Round 4
// 16.447 us; speedup vs baseline: 2.0038x; 1.8410x over previous
//
#include <hip/hip_runtime.h>

#define NBINS 64
#define FINE 512                     // 8 sub-bins per coarse bin
#define PIX_PER_CH (512 * 512)       // 262144
#define CH_TOTAL 24                  // 2 inputs x (4*3) channels
#define BLOCKS_PER_CH 32
#define PIX_PER_BLOCK (PIX_PER_CH / BLOCKS_PER_CH)   // 8192
#define THREADS 512                  // 8 waves
#define HBLOCKS (CH_TOTAL * BLOCKS_PER_CH)           // 768 = 3 per CU

#define O_LO (-36)                   // taps: d=(o+0.5)/8-0.5 in [-5,5); o in [-36,43]
#define NTAP 80
#define TAPS_PER_WAVE (NTAP / 8)     // 10

#define PAD(i) ((i) + ((i) >> 4))    // +1 pad per 16 words
#define PFINE (FINE + (FINE >> 4))   // 544

#define GPART_ROW (CH_TOTAL * NBINS) // 1536 floats per blk row
#define GPART_ROW4 (GPART_ROW / 4)   // 384 float4 per row

__device__ __forceinline__ float wexp(float d) {
    return __expf(-0.5f * d * d);
}

// Two kernel nodes, ZERO fill nodes, ZERO device-scope fences.
// R0/R2 post-mortems: fill nodes and per-block __threadfence releases are the
// ~10 us poison; the kernel boundary gives cross-XCD visibility for free.
// ws layout: [0, 196608) g_part f32 [blk][ch][bin]  (every slot plain-stored)

__global__ __launch_bounds__(THREADS) void hist_kernel(
        const float* __restrict__ pred, const float* __restrict__ target,
        float* __restrict__ g_part) {
    __shared__ int fineI[PFINE];     // padded per-block fine histogram
    __shared__ float hpart[NBINS];   // cross-wave partial coarse bins
    __shared__ int sLo, sHi;

    const int tid = threadIdx.x;
    const int lane = tid & 63, wave = tid >> 6;
    const int b = blockIdx.x;
    const int gch = b / BLOCKS_PER_CH;        // 0..23
    const int blk = b - gch * BLOCKS_PER_CH;  // 0..31
    const float4* src4 = reinterpret_cast<const float4*>(
        (gch < 12 ? pred + gch * PIX_PER_CH
                  : target + (gch - 12) * PIX_PER_CH)
        + blk * PIX_PER_BLOCK);

    for (int i = tid; i < PFINE; i += THREADS) fineI[i] = 0;
    if (tid < NBINS) hpart[tid] = 0.f;
    if (tid == 0) { sLo = 0; sHi = 0; }
    __syncthreads();

    // one memory epoch: all 4 float4 loads issued back-to-back, independent
    float4 v[4];
    #pragma unroll
    for (int it = 0; it < 4; ++it)
        v[it] = src4[it * THREADS + tid];

    const float HI = 1.0f - 1e-6f;
    int cLo = 0, cHi = 0;

    #pragma unroll
    for (int it = 0; it < 4; ++it) {
        float xs[4] = {v[it].x, v[it].y, v[it].z, v[it].w};
        #pragma unroll
        for (int k = 0; k < 4; ++k) {
            float y = fmaf(xs[k], 0.5f, 0.5f);
            if (y <= 0.f) {
                ++cLo;               // clipped: analytic fold, no scatter
            } else if (y >= HI) {
                ++cHi;
            } else {
                int f = (int)(y * (float)FINE);      // [0, 511]
                atomicAdd(&fineI[PAD(f)], 1);
            }
        }
    }

    // wave-reduce clip counts, one LDS atomic per wave
    #pragma unroll
    for (int off = 32; off; off >>= 1) {
        cLo += __shfl_down(cLo, off, 64);
        cHi += __shfl_down(cHi, off, 64);
    }
    if (lane == 0) {
        if (cLo) atomicAdd(&sLo, cLo);
        if (cHi) atomicAdd(&sHi, cHi);
    }
    __syncthreads();

    // Fused conv, bin-per-lane: lane owns coarse bin `lane`; wave w covers
    // taps [w*10, w*10+10). Read stride ~8.5 words -> ~2 lanes/bank (free).
    float acc = 0.f;
    #pragma unroll
    for (int s = 0; s < TAPS_PER_WAVE; ++s) {
        int o = O_LO + wave * TAPS_PER_WAVE + s;
        float d = fmaf((float)o + 0.5f, 0.125f, -0.5f);
        float kv = wexp(d);
        int idx = (lane << 3) + o;
        if (idx >= 0 && idx < FINE)
            acc = fmaf((float)fineI[PAD(idx)], kv, acc);
    }
    // fold clipped-pixel mass into edge bins analytically, per block (linear,
    // so identical to deferred folding). Verified absmax 0.0 in R0/R2.
    if (wave == 0) {
        if (lane <= 6)
            acc = fmaf((float)sLo, wexp(-0.5f - (float)lane), acc);
        if (lane >= 57) {
            float t = fmaf(HI, 64.f, -0.5f);
            acc = fmaf((float)sHi, wexp(t - (float)lane), acc);
        }
    }
    if (acc != 0.f) atomicAdd(&hpart[lane], acc);   // 8-way cross-wave combine
    __syncthreads();

    // coalesced 256 B row store: [blk][ch][bin]; every slot written -> no init
    if (tid < NBINS)
        g_part[blk * GPART_ROW + gch * NBINS + tid] = hpart[tid];
}

__global__ __launch_bounds__(512) void finalize_kernel(
        const float* __restrict__ g_part, float* __restrict__ out) {
    __shared__ float h[CH_TOTAL * NBINS];   // 1536
    __shared__ float csum[96];
    __shared__ float inv[CH_TOTAL];
    __shared__ float wred[8];
    const int tid = threadIdx.x;

    // sum the 32 per-block rows; fully coalesced (384 threads read consecutive
    // float4 within each 6 KB row), 32 independent loads per thread.
    if (tid < 384) {
        const float4* gp = reinterpret_cast<const float4*>(g_part) + tid;
        float4 s = make_float4(0.f, 0.f, 0.f, 0.f);
        #pragma unroll 8
        for (int r = 0; r < BLOCKS_PER_CH; ++r) {
            float4 w = gp[r * GPART_ROW4];
            s.x += w.x; s.y += w.y; s.z += w.z; s.w += w.w;
        }
        reinterpret_cast<float4*>(h)[tid] = s;
    }
    __syncthreads();

    // per-channel sums: 4 partial lanes per channel, then combine
    if (tid < 96) {
        int c = tid >> 2, q = tid & 3;
        float s = 0.f;
        #pragma unroll
        for (int j = 0; j < 16; ++j) s += h[c * NBINS + q * 16 + j];
        csum[tid] = s;
    }
    __syncthreads();
    if (tid < CH_TOTAL)
        inv[tid] = 1.0f / (csum[4 * tid] + csum[4 * tid + 1]
                         + csum[4 * tid + 2] + csum[4 * tid + 3] + 1e-8f);
    __syncthreads();

    float a2 = 0.f;
    for (int i = tid; i < 12 * NBINS; i += 512) {   // 768: 2 iters
        int c = i >> 6;
        float pa = h[i] * inv[c];
        float pb = h[12 * NBINS + i] * inv[12 + c];
        a2 += fabsf(pa - pb);
    }
    #pragma unroll
    for (int off = 32; off; off >>= 1) a2 += __shfl_down(a2, off, 64);
    if ((tid & 63) == 0) wred[tid >> 6] = a2;
    __syncthreads();
    if (tid == 0) {
        float total = 0.f;
        #pragma unroll
        for (int w2 = 0; w2 < 8; ++w2) total += wred[w2];
        out[0] = total * (1.0f / 768.0f);
    }
}

extern "C" void kernel_launch(void* const* d_in, const int* in_sizes, int n_in,
                              void* d_out, int out_size, void* d_ws, size_t ws_size,
                              hipStream_t stream) {
    const float* pred = (const float*)d_in[0];
    const float* target = (const float*)d_in[1];
    float* out = (float*)d_out;
    float* g_part = (float*)d_ws;                     // 49152 f32, all written

    hist_kernel<<<HBLOCKS, THREADS, 0, stream>>>(pred, target, g_part);
    finalize_kernel<<<1, 512, 0, stream>>>(g_part, out);
}